// Round 1
// baseline (40.139 us; speedup 1.0000x reference)
//
#include <hip/hip_runtime.h>

// Problem constants (match reference: B=8, N=8192, D=256, M=2)
#define NN 8192
#define DD 256
#define NH (NN / 2)
#define BB 8

__device__ __forceinline__ float4 f4_load(const float* p) {
    return *reinterpret_cast<const float4*>(p);
}
__device__ __forceinline__ float4 f4_scale(float s, float4 v) {
    return make_float4(s * v.x, s * v.y, s * v.z, s * v.w);
}
__device__ __forceinline__ float4 f4_fma(float s, float4 v, float4 a) {
    return make_float4(fmaf(s, v.x, a.x), fmaf(s, v.y, a.y),
                       fmaf(s, v.z, a.z), fmaf(s, v.w, a.w));
}

__global__ __launch_bounds__(256) void dhhp_kernel(
    const float* __restrict__ x,
    const float* __restrict__ gl_ii, const float* __restrict__ gl_ij,
    const float* __restrict__ gl_ji, const float* __restrict__ gl_jj,
    const float* __restrict__ gu_ii, const float* __restrict__ gu_ij,
    const float* __restrict__ gu_ji, const float* __restrict__ gu_jj,
    const float* __restrict__ diag, const int* __restrict__ transform,
    float* __restrict__ out)
{
    // one wave (64 lanes) per output row; 4 waves per block
    const int wid  = (blockIdx.x << 2) | (threadIdx.x >> 6);
    const int b    = wid >> 13;        // wid / NN
    const int j    = wid & (NN - 1);   // wid % NN
    const int lane = threadIdx.x & 63;
    const int col  = lane << 2;        // 4 floats per lane (float4)
    const int tr   = *transform;

    const float* xb   = x    + (size_t)b * NN * DD;
    const float* db   = diag + (size_t)b * NN;
    const float* uii  = gu_ii + (size_t)b * (NN - 1);
    const float* uij  = gu_ij + (size_t)b * (NN - 1);
    const float* uji  = gu_ji + (size_t)b * (NN - 1);
    const float* ujj  = gu_jj + (size_t)b * (NN - 1);
    const float* lii  = gl_ii + (size_t)b * (NN - 1);
    const float* lij  = gl_ij + (size_t)b * (NN - 1);
    const float* lji  = gl_ji + (size_t)b * (NN - 1);
    const float* ljj  = gl_jj + (size_t)b * (NN - 1);

    // load pre-processed row i of the sweep input:
    //   transform=1: stride-2 permuted input row
    //   transform=0: diag-scaled input row
    auto loadRow = [&](int i) -> float4 {
        int ic = i < 0 ? 0 : (i > NN - 1 ? NN - 1 : i);
        int r;
        if (tr) r = (ic < NH) ? (ic << 1) : (((ic - NH) << 1) | 1);
        else    r = ic;
        float4 v = f4_load(xb + (size_t)r * DD + col);
        if (!tr) v = f4_scale(db[ic], v);
        return v;
    };

    // upper sweep row i from the 3-row window (xm = xP[i-1], xc = xP[i], xp = xP[i+1])
    auto yRow = [&](int i, float4 xm, float4 xc, float4 xp) -> float4 {
        int ic = i < 0 ? 0 : (i > NN - 1 ? NN - 1 : i);
        if (ic == 0) {
            return f4_fma(uii[0], xc, f4_scale(uij[0], xp));
        } else if (ic == NN - 1) {
            return f4_fma(uji[NN - 2], xm, f4_scale(ujj[NN - 2], xc));
        } else {
            float lo  = uji[ic - 1];
            float cjj = ujj[ic - 1];
            float dm  = cjj * uii[ic];
            float hi  = cjj * uij[ic];
            float4 r = f4_scale(lo, xm);
            r = f4_fma(dm, xc, r);
            r = f4_fma(hi, xp, r);
            return r;
        }
    };

    // 5-row window of the (permuted / pre-scaled) input
    float4 xm2 = loadRow(j - 2);
    float4 xm1 = loadRow(j - 1);
    float4 x00 = loadRow(j);
    float4 xp1 = loadRow(j + 1);
    float4 xp2 = loadRow(j + 2);

    // three upper-sweep rows (edges handled inside yRow; unused edges are garbage-but-safe)
    float4 ym1 = yRow(j - 1, xm2, xm1, x00);
    float4 y00 = yRow(j,     xm1, x00, xp1);
    float4 yp1 = yRow(j + 1, x00, xp1, xp2);

    // lower sweep row j
    float4 z;
    if (j == 0) {
        z = f4_fma(lii[0], y00, f4_scale(lij[0], yp1));
    } else if (j == NN - 1) {
        z = f4_fma(lji[NN - 2], ym1, f4_scale(ljj[NN - 2], y00));
    } else {
        float ci = lii[j];
        float lo = ci * lji[j - 1];
        float dm = ci * ljj[j - 1];
        float hi = lij[j];
        z = f4_scale(lo, ym1);
        z = f4_fma(dm, y00, z);
        z = f4_fma(hi, yp1, z);
    }

    // postprocess + store
    int jo;
    float4 o;
    if (tr) {
        o  = f4_scale(db[j], z);
        jo = j;
    } else {
        o  = z;
        jo = (j & 1) ? (NH + (j >> 1)) : (j >> 1);  // inverse stride permutation
    }
    *reinterpret_cast<float4*>(out + (size_t)b * NN * DD + (size_t)jo * DD + col) = o;
}

extern "C" void kernel_launch(void* const* d_in, const int* in_sizes, int n_in,
                              void* d_out, int out_size, void* d_ws, size_t ws_size,
                              hipStream_t stream) {
    const float* x     = (const float*)d_in[0];
    const float* gl_ii = (const float*)d_in[1];
    const float* gl_ij = (const float*)d_in[2];
    const float* gl_ji = (const float*)d_in[3];
    const float* gl_jj = (const float*)d_in[4];
    const float* gu_ii = (const float*)d_in[5];
    const float* gu_ij = (const float*)d_in[6];
    const float* gu_ji = (const float*)d_in[7];
    const float* gu_jj = (const float*)d_in[8];
    const float* diag  = (const float*)d_in[9];
    const int* transform = (const int*)d_in[10];
    float* out = (float*)d_out;

    // one wave per (b, j) row; 4 waves (256 threads) per block
    dim3 grid(BB * NN / 4);
    dim3 block(256);
    hipLaunchKernelGGL(dhhp_kernel, grid, block, 0, stream,
                       x, gl_ii, gl_ij, gl_ji, gl_jj,
                       gu_ii, gu_ij, gu_ji, gu_jj, diag, transform, out);
}

// Round 2
// 38.750 us; speedup vs baseline: 1.0358x; 1.0358x over previous
//
#include <hip/hip_runtime.h>

// Problem constants (match reference: B=8, N=8192, D=256, M=2)
#define NN 8192
#define DD 256
#define NH (NN / 2)
#define BB 8
#define RPW 16   // output rows per wave (rolling window)
#define WPB 4    // waves per block

__device__ __forceinline__ float4 f4_load(const float* p) {
    return *reinterpret_cast<const float4*>(p);
}
__device__ __forceinline__ float4 f4_scale(float s, float4 v) {
    return make_float4(s * v.x, s * v.y, s * v.z, s * v.w);
}
__device__ __forceinline__ float4 f4_fma(float s, float4 v, float4 a) {
    return make_float4(fmaf(s, v.x, a.x), fmaf(s, v.y, a.y),
                       fmaf(s, v.z, a.z), fmaf(s, v.w, a.w));
}

__global__ __launch_bounds__(256) void dhhp_kernel(
    const float* __restrict__ x,
    const float* __restrict__ gl_ii, const float* __restrict__ gl_ij,
    const float* __restrict__ gl_ji, const float* __restrict__ gl_jj,
    const float* __restrict__ gu_ii, const float* __restrict__ gu_ij,
    const float* __restrict__ gu_ji, const float* __restrict__ gu_jj,
    const float* __restrict__ diag, const int* __restrict__ transform,
    float* __restrict__ out)
{
    // one wave per RPW consecutive output rows
    int wid = blockIdx.x * WPB + (threadIdx.x >> 6);
    wid = __builtin_amdgcn_readfirstlane(wid);          // provably wave-uniform -> scalar regs
    const int b    = wid >> 9;                          // wid / (NN/RPW), NN/RPW = 512
    const int j0   = (wid & 511) << 4;                  // * RPW
    const int lane = threadIdx.x & 63;
    const int col  = lane << 2;                         // float4 per lane
    const int tr   = *transform;

    const float* xb  = x    + (size_t)b * NN * DD;
    const float* db  = diag + (size_t)b * NN;
    const float* uii = gu_ii + (size_t)b * (NN - 1);
    const float* uij = gu_ij + (size_t)b * (NN - 1);
    const float* uji = gu_ji + (size_t)b * (NN - 1);
    const float* ujj = gu_jj + (size_t)b * (NN - 1);
    const float* lii = gl_ii + (size_t)b * (NN - 1);
    const float* lij = gl_ij + (size_t)b * (NN - 1);
    const float* lji = gl_ji + (size_t)b * (NN - 1);
    const float* ljj = gl_jj + (size_t)b * (NN - 1);
    float* ob = out + (size_t)b * NN * DD;

    auto permRow = [&](int i) -> int {
        return tr ? ((i < NH) ? (i << 1) : (((i - NH) << 1) | 1)) : i;
    };
    // interior (no clamp) pre-processed row load
    auto loadRowI = [&](int i) -> float4 {
        float4 v = f4_load(xb + (size_t)permRow(i) * DD + col);
        if (!tr) v = f4_scale(db[i], v);
        return v;
    };
    // clamped variant for edge waves
    auto loadRowC = [&](int i) -> float4 {
        int ic = i < 0 ? 0 : (i > NN - 1 ? NN - 1 : i);
        return loadRowI(ic);
    };
    // upper-sweep interior row i: y[i] = uji[i-1]*x[i-1] + ujj[i-1]*uii[i]*x[i] + ujj[i-1]*uij[i]*x[i+1]
    auto yInner = [&](int i, float4 xm, float4 xc, float4 xp) -> float4 {
        float lo  = uji[i - 1];
        float cjj = ujj[i - 1];
        float dm  = cjj * uii[i];
        float hi  = cjj * uij[i];
        float4 r = f4_scale(lo, xm);
        r = f4_fma(dm, xc, r);
        r = f4_fma(hi, xp, r);
        return r;
    };
    auto yAny = [&](int i, float4 xm, float4 xc, float4 xp) -> float4 {
        int ic = i < 0 ? 0 : (i > NN - 1 ? NN - 1 : i);
        if (ic == 0)      return f4_fma(uii[0], xc, f4_scale(uij[0], xp));
        if (ic == NN - 1) return f4_fma(uji[NN - 2], xm, f4_scale(ujj[NN - 2], xc));
        return yInner(ic, xm, xc, xp);
    };
    // lower-sweep interior row j: z[j] = lii[j]*lji[j-1]*y[j-1] + lii[j]*ljj[j-1]*y[j] + lij[j]*y[j+1]
    auto zInner = [&](int j, float4 ym, float4 yc, float4 yp) -> float4 {
        float ci = lii[j];
        float lo = ci * lji[j - 1];
        float dm = ci * ljj[j - 1];
        float hi = lij[j];
        float4 r = f4_scale(lo, ym);
        r = f4_fma(dm, yc, r);
        r = f4_fma(hi, yp, r);
        return r;
    };
    auto zAny = [&](int j, float4 ym, float4 yc, float4 yp) -> float4 {
        if (j == 0)      return f4_fma(lii[0], yc, f4_scale(lij[0], yp));
        if (j == NN - 1) return f4_fma(lji[NN - 2], ym, f4_scale(ljj[NN - 2], yc));
        return zInner(j, ym, yc, yp);
    };
    auto storeRow = [&](int j, float4 z) {
        int jo;
        float4 o;
        if (tr) { o = f4_scale(db[j], z); jo = j; }
        else    { o = z; jo = (j & 1) ? (NH + (j >> 1)) : (j >> 1); }
        *reinterpret_cast<float4*>(ob + (size_t)jo * DD + col) = o;
    };

    const bool interior = (j0 >= 2) && (j0 <= NN - RPW - 2);

    if (interior) {
        float4 xC = loadRowI(j0 - 2);
        float4 xD = loadRowI(j0 - 1);
        float4 xE = loadRowI(j0);
        float4 ym1, y00;
        {
            float4 xF = loadRowI(j0 + 1);
            ym1 = yInner(j0 - 1, xC, xD, xE);
            y00 = yInner(j0,     xD, xE, xF);
            xC = xE; xD = xF;   // xC = x[j0], xD = x[j0+1]
        }
        #pragma unroll
        for (int t = 0; t < RPW; ++t) {
            const int j = j0 + t;
            float4 xN  = loadRowI(j + 2);
            float4 yp1 = yInner(j + 1, xC, xD, xN);
            float4 z   = zInner(j, ym1, y00, yp1);
            storeRow(j, z);
            ym1 = y00; y00 = yp1; xC = xD; xD = xN;
        }
    } else {
        float4 xC = loadRowC(j0 - 2);
        float4 xD = loadRowC(j0 - 1);
        float4 xE = loadRowC(j0);
        float4 ym1, y00;
        {
            float4 xF = loadRowC(j0 + 1);
            ym1 = yAny(j0 - 1, xC, xD, xE);
            y00 = yAny(j0,     xD, xE, xF);
            xC = xE; xD = xF;
        }
        #pragma unroll
        for (int t = 0; t < RPW; ++t) {
            const int j = j0 + t;
            float4 xN  = loadRowC(j + 2);
            float4 yp1 = yAny(j + 1, xC, xD, xN);
            float4 z   = zAny(j, ym1, y00, yp1);
            storeRow(j, z);
            ym1 = y00; y00 = yp1; xC = xD; xD = xN;
        }
    }
}

extern "C" void kernel_launch(void* const* d_in, const int* in_sizes, int n_in,
                              void* d_out, int out_size, void* d_ws, size_t ws_size,
                              hipStream_t stream) {
    const float* x     = (const float*)d_in[0];
    const float* gl_ii = (const float*)d_in[1];
    const float* gl_ij = (const float*)d_in[2];
    const float* gl_ji = (const float*)d_in[3];
    const float* gl_jj = (const float*)d_in[4];
    const float* gu_ii = (const float*)d_in[5];
    const float* gu_ij = (const float*)d_in[6];
    const float* gu_ji = (const float*)d_in[7];
    const float* gu_jj = (const float*)d_in[8];
    const float* diag  = (const float*)d_in[9];
    const int* transform = (const int*)d_in[10];
    float* out = (float*)d_out;

    // total waves = BB * NN / RPW = 4096 ; 4 waves per block -> 1024 blocks
    dim3 grid(BB * NN / RPW / WPB);
    dim3 block(256);
    hipLaunchKernelGGL(dhhp_kernel, grid, block, 0, stream,
                       x, gl_ii, gl_ij, gl_ji, gl_jj,
                       gu_ii, gu_ij, gu_ji, gu_jj, diag, transform, out);
}

// Round 3
// 30.434 us; speedup vs baseline: 1.3189x; 1.2732x over previous
//
#include <hip/hip_runtime.h>

// Problem constants (match reference: B=8, N=8192, D=256, M=2)
#define NN 8192
#define DD 256
#define NH (NN / 2)
#define BB 8
#define RPW 8    // output rows per wave
#define WPB 4    // waves per block
#define NBLK (BB * NN / RPW / WPB)   // 2048
#define CPX (NBLK / 8)               // blocks per XCD chunk = 256

__device__ __forceinline__ float4 f4_load(const float* p) {
    return *reinterpret_cast<const float4*>(p);
}
__device__ __forceinline__ float4 f4_scale(float s, float4 v) {
    return make_float4(s * v.x, s * v.y, s * v.z, s * v.w);
}
__device__ __forceinline__ float4 f4_fma(float s, float4 v, float4 a) {
    return make_float4(fmaf(s, v.x, a.x), fmaf(s, v.y, a.y),
                       fmaf(s, v.z, a.z), fmaf(s, v.w, a.w));
}

__global__ __launch_bounds__(256, 4) void dhhp_kernel(
    const float* __restrict__ x,
    const float* __restrict__ gl_ii, const float* __restrict__ gl_ij,
    const float* __restrict__ gl_ji, const float* __restrict__ gl_jj,
    const float* __restrict__ gu_ii, const float* __restrict__ gu_ij,
    const float* __restrict__ gu_ji, const float* __restrict__ gu_jj,
    const float* __restrict__ diag, const int* __restrict__ transform,
    float* __restrict__ out)
{
    // XCD-aware swizzle: 2048 blocks -> each XCD gets a contiguous 256-block
    // chunk == exactly one batch b (8 MB in / 8 MB out): halo reuse stays in L2.
    const int bid  = blockIdx.x;
    const int swz  = (bid & 7) * CPX + (bid >> 3);
    int wid = swz * WPB + (threadIdx.x >> 6);
    wid = __builtin_amdgcn_readfirstlane(wid);       // wave-uniform -> SGPRs
    const int b    = wid >> 10;                      // waves per batch = NN/RPW = 1024
    const int j0   = (wid & 1023) << 3;              // * RPW
    const int col  = (threadIdx.x & 63) << 2;        // float4 per lane
    const int tr   = *transform;

    const float* xb  = x    + (size_t)b * NN * DD;
    const float* db  = diag + (size_t)b * NN;
    const float* uii = gu_ii + (size_t)b * (NN - 1);
    const float* uij = gu_ij + (size_t)b * (NN - 1);
    const float* uji = gu_ji + (size_t)b * (NN - 1);
    const float* ujj = gu_jj + (size_t)b * (NN - 1);
    const float* lii = gl_ii + (size_t)b * (NN - 1);
    const float* lij = gl_ij + (size_t)b * (NN - 1);
    const float* lji = gl_ji + (size_t)b * (NN - 1);
    const float* ljj = gl_jj + (size_t)b * (NN - 1);
    float* ob = out + (size_t)b * NN * DD;

    auto permRow = [&](int i) -> int {
        return tr ? ((i < NH) ? (i << 1) : (((i - NH) << 1) | 1)) : i;
    };
    auto loadRowI = [&](int i) -> float4 {           // interior: no clamp
        float4 v = f4_load(xb + (size_t)permRow(i) * DD + col);
        if (!tr) v = f4_scale(db[i], v);
        return v;
    };
    auto loadRowC = [&](int i) -> float4 {           // edge: clamped
        int ic = i < 0 ? 0 : (i > NN - 1 ? NN - 1 : i);
        return loadRowI(ic);
    };
    auto yInner = [&](int i, float4 xm, float4 xc, float4 xp) -> float4 {
        float lo  = uji[i - 1];
        float cjj = ujj[i - 1];
        float dm  = cjj * uii[i];
        float hi  = cjj * uij[i];
        float4 r = f4_scale(lo, xm);
        r = f4_fma(dm, xc, r);
        r = f4_fma(hi, xp, r);
        return r;
    };
    // NOTE: ghost rows (i<0 or i>N-1 after clamp) produce wrong-but-unused values.
    auto yAny = [&](int i, float4 xm, float4 xc, float4 xp) -> float4 {
        int ic = i < 0 ? 0 : (i > NN - 1 ? NN - 1 : i);
        if (ic == 0)      return f4_fma(uii[0], xc, f4_scale(uij[0], xp));
        if (ic == NN - 1) return f4_fma(uji[NN - 2], xm, f4_scale(ujj[NN - 2], xc));
        return yInner(ic, xm, xc, xp);
    };
    auto zInner = [&](int j, float4 ym, float4 yc, float4 yp) -> float4 {
        float ci = lii[j];
        float lo = ci * lji[j - 1];
        float dm = ci * ljj[j - 1];
        float hi = lij[j];
        float4 r = f4_scale(lo, ym);
        r = f4_fma(dm, yc, r);
        r = f4_fma(hi, yp, r);
        return r;
    };
    auto zAny = [&](int j, float4 ym, float4 yc, float4 yp) -> float4 {
        if (j == 0)      return f4_fma(lii[0], yc, f4_scale(lij[0], yp));
        if (j == NN - 1) return f4_fma(lji[NN - 2], ym, f4_scale(ljj[NN - 2], yc));
        return zInner(j, ym, yc, yp);
    };
    auto storeRow = [&](int j, float4 z) {
        int jo;
        float4 o;
        if (tr) { o = f4_scale(db[j], z); jo = j; }
        else    { o = z; jo = (j & 1) ? (NH + (j >> 1)) : (j >> 1); }
        *reinterpret_cast<float4*>(ob + (size_t)jo * DD + col) = o;
    };

    const bool interior = (j0 >= 2) && (j0 <= NN - RPW - 2);

    float4 xr[RPW + 4];   // x[j0-2 .. j0+RPW+1]
    float4 yr[RPW + 2];   // y[j0-1 .. j0+RPW]

    if (interior) {
        // 1) issue ALL window loads back-to-back (12 independent 16B loads in flight)
        #pragma unroll
        for (int t = 0; t < RPW + 4; ++t) xr[t] = loadRowI(j0 - 2 + t);
        // 2) upper sweep
        #pragma unroll
        for (int t = 0; t < RPW + 2; ++t)
            yr[t] = yInner(j0 - 1 + t, xr[t], xr[t + 1], xr[t + 2]);
        // 3) lower sweep + store
        #pragma unroll
        for (int t = 0; t < RPW; ++t)
            storeRow(j0 + t, zInner(j0 + t, yr[t], yr[t + 1], yr[t + 2]));
    } else {
        #pragma unroll
        for (int t = 0; t < RPW + 4; ++t) xr[t] = loadRowC(j0 - 2 + t);
        #pragma unroll
        for (int t = 0; t < RPW + 2; ++t)
            yr[t] = yAny(j0 - 1 + t, xr[t], xr[t + 1], xr[t + 2]);
        #pragma unroll
        for (int t = 0; t < RPW; ++t)
            storeRow(j0 + t, zAny(j0 + t, yr[t], yr[t + 1], yr[t + 2]));
    }
}

extern "C" void kernel_launch(void* const* d_in, const int* in_sizes, int n_in,
                              void* d_out, int out_size, void* d_ws, size_t ws_size,
                              hipStream_t stream) {
    const float* x     = (const float*)d_in[0];
    const float* gl_ii = (const float*)d_in[1];
    const float* gl_ij = (const float*)d_in[2];
    const float* gl_ji = (const float*)d_in[3];
    const float* gl_jj = (const float*)d_in[4];
    const float* gu_ii = (const float*)d_in[5];
    const float* gu_ij = (const float*)d_in[6];
    const float* gu_ji = (const float*)d_in[7];
    const float* gu_jj = (const float*)d_in[8];
    const float* diag  = (const float*)d_in[9];
    const int* transform = (const int*)d_in[10];
    float* out = (float*)d_out;

    dim3 grid(NBLK);      // 2048 blocks, 4 waves each
    dim3 block(256);
    hipLaunchKernelGGL(dhhp_kernel, grid, block, 0, stream,
                       x, gl_ii, gl_ij, gl_ji, gl_jj,
                       gu_ii, gu_ij, gu_ji, gu_jj, diag, transform, out);
}